// Round 5
// baseline (230.245 us; speedup 1.0000x reference)
//
#include <hip/hip_runtime.h>
#include <hip/hip_bf16.h>

#define NB   32
#define NT   784
#define NC   768
#define NH   4
#define CH   192
#define PSZ  14
#define NP   196
#define RESO 28
#define EPSV 1e-5f
#define JT   4
#define NF4  192   // float4s per token (NC/4)

// ---------------------------------------------------------------------------
// K1: position softmax -> posT[h][j][i] + sigmoid gates.
// grid = NH*NP blocks of 64; bid = h*NP + j.
// ---------------------------------------------------------------------------
__global__ __launch_bounds__(64) void k_pos(
    const float* __restrict__ pos_w, const float* __restrict__ pos_b,
    const float* __restrict__ mnw,   const float* __restrict__ vnw,
    float* __restrict__ posT, float* __restrict__ mwvw) {
  int bid = blockIdx.x;
  int h = bid / NP, j = bid % NP;
  int lane = threadIdx.x;

  if (bid == 0 && lane < 8) {
    float v = (lane < 4) ? mnw[lane] : vnw[lane - 4];
    mwvw[lane] = 1.f / (1.f + expf(-v));
  }

  float w0 = pos_w[h * 3 + 0];
  float w1 = pos_w[h * 3 + 1];
  float w2 = pos_w[h * 3 + 2];
  float pb = pos_b[h];
  int jx = j % PSZ, jy = j / PSZ;

  float mx = -1e30f;
  for (int i = lane; i < NP; i += 64) {
    float ix = (float)(jx - (i % PSZ));
    float iy = (float)(jy - (i / PSZ));
    float s = ix * w0 + iy * w1 + (ix * ix + iy * iy) * w2 + pb;
    mx = fmaxf(mx, s);
  }
  for (int d = 32; d >= 1; d >>= 1) mx = fmaxf(mx, __shfl_down(mx, d, 64));
  mx = __shfl(mx, 0, 64);

  float sum = 0.f;
  for (int i = lane; i < NP; i += 64) {
    float ix = (float)(jx - (i % PSZ));
    float iy = (float)(jy - (i / PSZ));
    float s = ix * w0 + iy * w1 + (ix * ix + iy * iy) * w2 + pb;
    sum += expf(s - mx);
  }
  for (int d = 32; d >= 1; d >>= 1) sum += __shfl_down(sum, d, 64);
  sum = __shfl(sum, 0, 64);
  float inv = 1.f / sum;

  for (int i = lane; i < NP; i += 64) {
    float ix = (float)(jx - (i % PSZ));
    float iy = (float)(jy - (i / PSZ));
    float s = ix * w0 + iy * w1 + (ix * ix + iy * iy) * w2 + pb;
    posT[((size_t)h * NP + j) * NP + i] = expf(s - mx) * inv;
  }
}

// ---------------------------------------------------------------------------
// K2: wave-per-token group-m2 norm + per-token mean/var + 2x2 pool.
// grid = NB*NP blocks of 256 (4 waves = 4 tokens of one patch).
// (unchanged from R4 — control; expect its counters in next round's top-5)
// ---------------------------------------------------------------------------
__global__ __launch_bounds__(256) void k_norm_pool(
    const float* __restrict__ x,
    float* __restrict__ inv_m2, float* __restrict__ mean_ln,
    float* __restrict__ var_ln, float4* __restrict__ xp4) {
  __shared__ float4 xl4[4 * NF4];  // 12.3 KB
  int bid = blockIdx.x;
  int b = bid / NP, ip = bid % NP;
  int pr = ip / PSZ, pc = ip % PSZ;
  int tid = threadIdx.x;
  int k = tid >> 6, lane = tid & 63;
  int t = (2 * pr + (k >> 1)) * RESO + (2 * pc + (k & 1));

  const float4* row = (const float4*)(x + (size_t)(b * NT + t) * NC);
  float4 v0 = row[lane], v1 = row[lane + 64], v2 = row[lane + 128];
  int h0 = lane / 48;
  int h1 = (lane + 64) / 48;
  int h2 = (lane + 128) / 48;

  float d0 = v0.x * v0.x + v0.y * v0.y + v0.z * v0.z + v0.w * v0.w;
  float d1 = v1.x * v1.x + v1.y * v1.y + v1.z * v1.z + v1.w * v1.w;
  float d2 = v2.x * v2.x + v2.y * v2.y + v2.z * v2.z + v2.w * v2.w;
  float s0 = (h0 == 0) ? d0 : 0.f;
  float s1 = ((h0 == 1) ? d0 : 0.f) + ((h1 == 1) ? d1 : 0.f);
  float s2 = ((h1 == 2) ? d1 : 0.f) + ((h2 == 2) ? d2 : 0.f);
  float s3 = (h2 == 3) ? d2 : 0.f;
#pragma unroll
  for (int d = 32; d >= 1; d >>= 1) {
    s0 += __shfl_xor(s0, d, 64);
    s1 += __shfl_xor(s1, d, 64);
    s2 += __shfl_xor(s2, d, 64);
    s3 += __shfl_xor(s3, d, 64);
  }
  float i0 = rsqrtf(s0 * (1.f / CH) + EPSV);
  float i1 = rsqrtf(s1 * (1.f / CH) + EPSV);
  float i2 = rsqrtf(s2 * (1.f / CH) + EPSV);
  float i3 = rsqrtf(s3 * (1.f / CH) + EPSV);
  if (lane < 4) {
    float iv = (lane == 0) ? i0 : (lane == 1) ? i1 : (lane == 2) ? i2 : i3;
    inv_m2[(size_t)(b * NT + t) * NH + lane] = iv;
  }

  float f0 = (h0 == 0) ? i0 : i1;
  float f1 = (h1 == 1) ? i1 : i2;
  float f2 = (h2 == 2) ? i2 : i3;
  v0.x *= f0; v0.y *= f0; v0.z *= f0; v0.w *= f0;
  v1.x *= f1; v1.y *= f1; v1.z *= f1; v1.w *= f1;
  v2.x *= f2; v2.y *= f2; v2.z *= f2; v2.w *= f2;

  float sm = v0.x + v0.y + v0.z + v0.w + v1.x + v1.y + v1.z + v1.w +
             v2.x + v2.y + v2.z + v2.w;
  float sq = v0.x * v0.x + v0.y * v0.y + v0.z * v0.z + v0.w * v0.w +
             v1.x * v1.x + v1.y * v1.y + v1.z * v1.z + v1.w * v1.w +
             v2.x * v2.x + v2.y * v2.y + v2.z * v2.z + v2.w * v2.w;
#pragma unroll
  for (int d = 32; d >= 1; d >>= 1) {
    sm += __shfl_xor(sm, d, 64);
    sq += __shfl_xor(sq, d, 64);
  }
  if (lane == 0) {
    float mean = sm / (float)NC;
    mean_ln[b * NT + t] = mean;
    var_ln[b * NT + t] = (sq - (float)NC * mean * mean) / (float)(NC - 1);
  }

  xl4[k * NF4 + lane] = v0;
  xl4[k * NF4 + lane + 64] = v1;
  xl4[k * NF4 + lane + 128] = v2;
  __syncthreads();

  if (tid < NF4) {
    float4 a = xl4[tid], bb = xl4[NF4 + tid], c = xl4[2 * NF4 + tid],
           d = xl4[3 * NF4 + tid];
    float4 r;
    r.x = (a.x + bb.x + c.x + d.x) * 0.25f;
    r.y = (a.y + bb.y + c.y + d.y) * 0.25f;
    r.z = (a.z + bb.z + c.z + d.z) * 0.25f;
    r.w = (a.w + bb.w + c.w + d.w) * 0.25f;
    xp4[(size_t)(b * NP + ip) * NF4 + tid] = r;
  }
}

// ---------------------------------------------------------------------------
// K3: fused einsum + blend + affine + store.
// grid = NB*(NP/JT) blocks of 192 (3 waves). Thread = one float4 of channels
// (p = tid in [0,192), channels 4p..4p+3, head h = p/48).
// Weights in LDS as wlT[h][i][jj] -> one broadcast ds_read_b128 per i.
// xp loads are one global b128 per i per thread.
// ---------------------------------------------------------------------------
__global__ __launch_bounds__(192) void k_einsum_out(
    const float4* __restrict__ xp4, const float* __restrict__ posT,
    const float4* __restrict__ x4, const float4* __restrict__ weight4,
    const float4* __restrict__ bias4, const float* __restrict__ inv_m2,
    const float* __restrict__ mean_ln, const float* __restrict__ var_ln,
    const float* __restrict__ mwvw, float4* __restrict__ out4) {
  __shared__ float wlT[NH * NP * JT];  // [h][i][jj], 12.5 KB
  __shared__ float tstat[JT][4][6];
  int bid = blockIdx.x;
  int b = bid / (NP / JT), jt = bid % (NP / JT);
  int tid = threadIdx.x;
  int j0 = jt * JT;
  int p = tid;          // float4 index 0..191
  int h = p / 48;       // head

  // stage weights: read posT coalesced (i fastest), scatter to [h][i][jj]
  for (int idx = tid; idx < NH * NP * JT; idx += 192) {
    int hh = idx / (NP * JT);
    int rem = idx % (NP * JT);
    int jj = rem / NP, i = rem % NP;
    wlT[(hh * NP + i) * JT + jj] = posT[((size_t)hh * NP + (j0 + jj)) * NP + i];
  }
  if (tid < JT * 4 * 6) {
    int jj = tid / 24, rem = tid % 24, kk = rem / 6, f = rem % 6;
    int j = j0 + jj;
    int t = (2 * (j / PSZ) + (kk >> 1)) * RESO + (2 * (j % PSZ) + (kk & 1));
    size_t o = (size_t)(b * NT + t);
    tstat[jj][kk][f] = (f < 4) ? inv_m2[o * NH + f]
                     : (f == 4) ? mean_ln[o] : var_ln[o];
  }
  __syncthreads();

  float4 a1[JT], a2[JT];
#pragma unroll
  for (int jj = 0; jj < JT; ++jj) {
    a1[jj] = make_float4(0.f, 0.f, 0.f, 0.f);
    a2[jj] = make_float4(0.f, 0.f, 0.f, 0.f);
  }
  const float4* base = xp4 + (size_t)b * NP * NF4;

#pragma unroll 2
  for (int i = 0; i < NP; ++i) {
    float4 w4 = *(const float4*)&wlT[(h * NP + i) * JT];   // broadcast b128
    float4 v = base[(size_t)i * NF4 + p];                  // global b128
    float4 q;
    q.x = v.x * v.x; q.y = v.y * v.y; q.z = v.z * v.z; q.w = v.w * v.w;
#pragma unroll
    for (int jj = 0; jj < JT; ++jj) {
      float ww = (jj == 0) ? w4.x : (jj == 1) ? w4.y : (jj == 2) ? w4.z : w4.w;
      a1[jj].x += ww * v.x; a1[jj].y += ww * v.y;
      a1[jj].z += ww * v.z; a1[jj].w += ww * v.w;
      a2[jj].x += ww * q.x; a2[jj].y += ww * q.y;
      a2[jj].z += ww * q.z; a2[jj].w += ww * q.w;
    }
  }

  // epilogue
  float4 wv = weight4[p], bv = bias4[p];
  float mw = mwvw[h], vw = mwvw[4 + h];
  float omw = 1.f - mw, ovw = 1.f - vw;

#pragma unroll
  for (int jj = 0; jj < JT; ++jj) {
    int j = j0 + jj;
    float4 m = a1[jj];
    float4 pv;
    pv.x = fmaxf(a2[jj].x - m.x * m.x, 0.f);
    pv.y = fmaxf(a2[jj].y - m.y * m.y, 0.f);
    pv.z = fmaxf(a2[jj].z - m.z * m.z, 0.f);
    pv.w = fmaxf(a2[jj].w - m.w * m.w, 0.f);
#pragma unroll
    for (int kk = 0; kk < 4; ++kk) {
      int t = (2 * (j / PSZ) + (kk >> 1)) * RESO + (2 * (j % PSZ) + (kk & 1));
      size_t xo = (size_t)(b * NT + t) * NF4 + p;
      float iv = tstat[jj][kk][h];
      float ml = tstat[jj][kk][4], vl = tstat[jj][kk][5];
      float4 xv = x4[xo];

      float mrx = omw * m.x + mw * ml, mry = omw * m.y + mw * ml;
      float mrz = omw * m.z + mw * ml, mrw = omw * m.w + mw * ml;
      float vrx = ovw * pv.x + vw * vl, vry = ovw * pv.y + vw * vl;
      float vrz = ovw * pv.z + vw * vl, vrw = ovw * pv.w + vw * vl;

      float4 o;
      o.x = (xv.x * iv - mrx) * rsqrtf(vrx + EPSV) * wv.x + bv.x;
      o.y = (xv.y * iv - mry) * rsqrtf(vry + EPSV) * wv.y + bv.y;
      o.z = (xv.z * iv - mrz) * rsqrtf(vrz + EPSV) * wv.z + bv.z;
      o.w = (xv.w * iv - mrw) * rsqrtf(vrw + EPSV) * wv.w + bv.w;
      out4[xo] = o;
    }
  }
}

// ---------------------------------------------------------------------------
extern "C" void kernel_launch(void* const* d_in, const int* in_sizes, int n_in,
                              void* d_out, int out_size, void* d_ws, size_t ws_size,
                              hipStream_t stream) {
  const float* x     = (const float*)d_in[0];
  const float* wgt   = (const float*)d_in[1];
  const float* bias  = (const float*)d_in[2];
  const float* mnw   = (const float*)d_in[3];
  const float* vnw   = (const float*)d_in[4];
  const float* pos_w = (const float*)d_in[5];
  const float* pos_b = (const float*)d_in[6];
  float* out = (float*)d_out;

  float* ws      = (float*)d_ws;
  float* posT    = ws;                              // NH*NP*NP = 153664
  float* mwvw    = posT + (size_t)NH * NP * NP;     // 8
  float* inv_m2  = mwvw + 8;                        // NB*NT*NH = 100352
  float* mean_ln = inv_m2 + (size_t)NB * NT * NH;   // 25088
  float* var_ln  = mean_ln + (size_t)NB * NT;       // 25088
  float* xp      = var_ln + (size_t)NB * NT + 24;   // pad to 16B alignment
  // total ~20.5 MB of workspace

  hipLaunchKernelGGL(k_pos, dim3(NH * NP), dim3(64), 0, stream,
                     pos_w, pos_b, mnw, vnw, posT, mwvw);
  hipLaunchKernelGGL(k_norm_pool, dim3(NB * NP), dim3(256), 0, stream,
                     x, inv_m2, mean_ln, var_ln, (float4*)xp);
  hipLaunchKernelGGL(k_einsum_out, dim3(NB * (NP / JT)), dim3(192), 0, stream,
                     (const float4*)xp, posT, (const float4*)x,
                     (const float4*)wgt, (const float4*)bias,
                     inv_m2, mean_ln, var_ln, mwvw, (float4*)out);
}